// Round 7
// baseline (357.070 us; speedup 1.0000x reference)
//
#include <hip/hip_runtime.h>

// x        [64, 524288] f32 | idx_feat [4096,256] f32 | weight [64,256] f32
// bias     [64] f32         | pred_cate [4096] i32    | pred_score [4096] f32
// out (f32 concat): seg_pred [53*524288], unique_cate [53], fused_score [53]

#define KK   4096
#define CIN  256
#define CC   64
#define HW   524288   // 512*1024
#define HW4  (HW / 4) // float4 columns
#define UU   53
#define FWS  56       // fwt row stride (reads reach col 55 for quarter 3)
#define UH   14       // classes per u-quarter (14,14,14,11)

// ws layout (floats) — only fwt; no atomics, no memset needed
#define WS_FWT 0      // fw TRANSPOSED [64][FWS]

typedef float f4 __attribute__((ext_vector_type(4)));

// ---------------------------------------------------------------------------
// Fused stages 1+2: one block per class u (53 blocks, 256 thr).
// CHANGED: block 0 also zeroes fwt pad cols 53..55 (quarter 3 of seg_pred
// reads them into never-stored accumulators; keep them clean, not 0xAA).
// ---------------------------------------------------------------------------
__global__ __launch_bounds__(256)
void fused12_kernel(const float* __restrict__ idx_feat,
                    const int*   __restrict__ pred_cate,
                    const float* __restrict__ pred_score,
                    const float* __restrict__ weight,
                    const float* __restrict__ bias,
                    float* __restrict__ ws,
                    float* __restrict__ out)
{
    const int u   = blockIdx.x;
    const int tid = threadIdx.x;

    __shared__ int   list[128];    // max count per class is 78 (4096 = 53*77+15)
    __shared__ int   nmatch;
    __shared__ float sumf[CIN];    // per-cin class feature sums
    __shared__ float wsum[4];      // per-wave score partials

    if (u == 0 && tid < CC) {      // zero pad cols (disjoint from all col stores)
        ws[WS_FWT + tid * FWS + 53] = 0.0f;
        ws[WS_FWT + tid * FWS + 54] = 0.0f;
        ws[WS_FWT + tid * FWS + 55] = 0.0f;
    }

    if (tid == 0) nmatch = 0;
    __syncthreads();

    // ---- Phase A: scan + compact + score ----
    float sc = 0.0f;
    #pragma unroll
    for (int k = tid; k < KK; k += 256) {       // coalesced int loads
        if (pred_cate[k] == u) {
            int pos = atomicAdd(&nmatch, 1);    // LDS atomic, ~77/block total
            list[pos] = k;
            sc += pred_score[k];
        }
    }
    // wave-reduce score (64 lanes)
    #pragma unroll
    for (int off = 32; off > 0; off >>= 1) sc += __shfl_down(sc, off);
    if ((tid & 63) == 0) wsum[tid >> 6] = sc;
    __syncthreads();                            // list + wsum complete

    // ---- Phase B: feature sums, thread owns cin = tid ----
    const int n = nmatch;                       // uniform
    float acc = 0.0f;
    #pragma unroll 4
    for (int m = 0; m < n; ++m) {
        const int k = list[m];                  // uniform LDS broadcast
        acc += idx_feat[(size_t)k * CIN + tid]; // coalesced row load
    }
    sumf[tid] = acc;
    __syncthreads();

    // ---- Phase C: fw[:,u] = (weight @ mean_u) + bias, transposed store ----
    const float inv = 1.0f / (float)n;
    const int c = tid >> 2;                     // output channel 0..63
    const int q = tid & 3;                      // quarter of the 256-dot
    float d = 0.0f;
    const int i0 = q * 64;
    #pragma unroll 8
    for (int i = 0; i < 64; ++i)
        d = fmaf(sumf[i0 + i], weight[(size_t)c * CIN + i0 + i], d);
    d += __shfl_xor(d, 1);
    d += __shfl_xor(d, 2);                      // q-group of 4 summed
    if (q == 0)
        ws[WS_FWT + c * FWS + u] = d * inv + bias[c];

    if (tid == 0) {
        out[(size_t)UU * HW + u]      = (float)u;                       // unique_cate
        out[(size_t)UU * HW + UU + u] = (wsum[0] + wsum[1] + wsum[2] + wsum[3]) * inv; // fused_score
    }
}

// ---------------------------------------------------------------------------
// Stage 3: seg_pred = fw [53,64] @ x [64, HW], u-SPLIT 4-way.
// Gradient from rounds 3-6: per-wave register footprint -> TLP is THE lever.
//  r6 (2-way, 108 acc): allocator put accs in AGPR (60 VGPR + ~108 AGPR =
//  ~168 unified) -> 3 waves/SIMD, 33% occupancy, 79.7 us, both pipes <40%.
// This version: acc = 14 f4 = 56 regs; unroll 4 (4 loads in flight/thread);
// total need ~84-116 unified -> 6-8 waves/SIMD. x streamed 4x but r6 PROVED
// L3 absorbs repeat passes (FETCH stayed 134 MB over 2 passes); 4 same-j
// sibling blocks run concurrently. Plain cached loads for x; nt stores.
// Per-output FMA chain unchanged -> bit-identical.
// Floors: mem 245 MB @ ~6.7 TB/s = 37 us; VALU ~24 us.
// ---------------------------------------------------------------------------
__global__ __launch_bounds__(256, 4)
void seg_pred_kernel(const float* __restrict__ x,
                     const float* __restrict__ ws,
                     float* __restrict__ out)
{
    const int b    = blockIdx.x;
    const int half = b & 3;
    const int j    = (b >> 2) * 256 + threadIdx.x;  // float4 column index
    const int u0   = half * UH;                     // 0, 14, 28, 42
    const f4* x4   = (const f4*)x;
    f4*       out4 = (f4*)out;
    const float* fwt = ws + WS_FWT + u0;

    f4 acc[UH];
    #pragma unroll
    for (int u = 0; u < UH; ++u) acc[u] = (f4)0.0f;

    #pragma unroll 4
    for (int c = 0; c < CC; ++c) {
        const f4 xv = x4[(size_t)c * HW4 + j];       // plain load: L2/L3 allocate
        #pragma unroll
        for (int u = 0; u < UH; ++u) {
            const float w = fwt[c * FWS + u];        // uniform, consecutive
            acc[u].x = fmaf(w, xv.x, acc[u].x);      // (quarter 3, u>=11 reads
            acc[u].y = fmaf(w, xv.y, acc[u].y);      //  zeroed pad cols 53-55,
            acc[u].z = fmaf(w, xv.z, acc[u].z);      //  never stored)
            acc[u].w = fmaf(w, xv.w, acc[u].w);
        }
    }

    #pragma unroll
    for (int u = 0; u < UH; ++u)
        if (u0 + u < UU)                             // quarter 3 stores 11 rows
            __builtin_nontemporal_store(acc[u], &out4[(size_t)(u0 + u) * HW4 + j]);
}

extern "C" void kernel_launch(void* const* d_in, const int* in_sizes, int n_in,
                              void* d_out, int out_size, void* d_ws, size_t ws_size,
                              hipStream_t stream)
{
    const float* x          = (const float*)d_in[0];
    const float* idx_feat   = (const float*)d_in[1];
    const float* weight     = (const float*)d_in[2];
    const float* bias       = (const float*)d_in[3];
    const int*   pred_cate  = (const int*)d_in[4];
    const float* pred_score = (const float*)d_in[5];

    float* out = (float*)d_out;
    float* ws  = (float*)d_ws;

    fused12_kernel<<<UU, 256, 0, stream>>>(idx_feat, pred_cate, pred_score,
                                           weight, bias, ws, out);
    seg_pred_kernel<<<4 * (HW4 / 256), 256, 0, stream>>>(x, ws, out);  // 2048 blocks
}

// Round 8
// 319.536 us; speedup vs baseline: 1.1175x; 1.1175x over previous
//
#include <hip/hip_runtime.h>

// x        [64, 524288] f32 | idx_feat [4096,256] f32 | weight [64,256] f32
// bias     [64] f32         | pred_cate [4096] i32    | pred_score [4096] f32
// out (f32 concat): seg_pred [53*524288], unique_cate [53], fused_score [53]

#define KK   4096
#define CIN  256
#define CC   64
#define HW   524288   // 512*1024
#define HW4  (HW / 4) // float4 columns
#define UU   53
#define FWS  56       // fwt row stride (wave 3 reads pad cols 53-55: zeroed)
#define JT   64       // float4 columns per block (= 1 wave's lanes)
#define UQ   14       // u-classes per wave (waves 0-2: 14, wave 3: 11)
#define NCH  16       // chunks of 4 c-planes (16*4 = 64 = CC)

// ws layout (floats) — only fwt; no atomics, no memset needed
#define WS_FWT 0      // fw TRANSPOSED [64][FWS]

typedef float f4 __attribute__((ext_vector_type(4)));

// ---------------------------------------------------------------------------
// Fused stages 1+2 (UNCHANGED from round 6, incl. pad-col zeroing).
// ---------------------------------------------------------------------------
__global__ __launch_bounds__(256)
void fused12_kernel(const float* __restrict__ idx_feat,
                    const int*   __restrict__ pred_cate,
                    const float* __restrict__ pred_score,
                    const float* __restrict__ weight,
                    const float* __restrict__ bias,
                    float* __restrict__ ws,
                    float* __restrict__ out)
{
    const int u   = blockIdx.x;
    const int tid = threadIdx.x;

    __shared__ int   list[128];    // max count per class is 78 (4096 = 53*77+15)
    __shared__ int   nmatch;
    __shared__ float sumf[CIN];    // per-cin class feature sums
    __shared__ float wsum[4];      // per-wave score partials

    if (u == 0 && tid < CC) {      // zero pad cols (disjoint from all col stores)
        ws[WS_FWT + tid * FWS + 53] = 0.0f;
        ws[WS_FWT + tid * FWS + 54] = 0.0f;
        ws[WS_FWT + tid * FWS + 55] = 0.0f;
    }

    if (tid == 0) nmatch = 0;
    __syncthreads();

    // ---- Phase A: scan + compact + score ----
    float sc = 0.0f;
    #pragma unroll
    for (int k = tid; k < KK; k += 256) {       // coalesced int loads
        if (pred_cate[k] == u) {
            int pos = atomicAdd(&nmatch, 1);    // LDS atomic, ~77/block total
            list[pos] = k;
            sc += pred_score[k];
        }
    }
    // wave-reduce score (64 lanes)
    #pragma unroll
    for (int off = 32; off > 0; off >>= 1) sc += __shfl_down(sc, off);
    if ((tid & 63) == 0) wsum[tid >> 6] = sc;
    __syncthreads();                            // list + wsum complete

    // ---- Phase B: feature sums, thread owns cin = tid ----
    const int n = nmatch;                       // uniform
    float acc = 0.0f;
    #pragma unroll 4
    for (int m = 0; m < n; ++m) {
        const int k = list[m];                  // uniform LDS broadcast
        acc += idx_feat[(size_t)k * CIN + tid]; // coalesced row load
    }
    sumf[tid] = acc;
    __syncthreads();

    // ---- Phase C: fw[:,u] = (weight @ mean_u) + bias, transposed store ----
    const float inv = 1.0f / (float)n;
    const int c = tid >> 2;                     // output channel 0..63
    const int q = tid & 3;                      // quarter of the 256-dot
    float d = 0.0f;
    const int i0 = q * 64;
    #pragma unroll 8
    for (int i = 0; i < 64; ++i)
        d = fmaf(sumf[i0 + i], weight[(size_t)c * CIN + i0 + i], d);
    d += __shfl_xor(d, 1);
    d += __shfl_xor(d, 2);                      // q-group of 4 summed
    if (q == 0)
        ws[WS_FWT + c * FWS + u] = d * inv + bias[c];

    if (tid == 0) {
        out[(size_t)UU * HW + u]      = (float)u;                       // unique_cate
        out[(size_t)UU * HW + UU + u] = (wsum[0] + wsum[1] + wsum[2] + wsum[3]) * inv; // fused_score
    }
}

// ---------------------------------------------------------------------------
// Stage 3: seg_pred = fw [53,64] @ x [64, HW] — intra-block u-split.
// Lesson r2/r6/r7: inter-block u-split multiplies x read traffic (r7: 4-way
// -> 524 MB demand, 197 us); no-split needs 212 acc regs (allocator cliff).
// Decouple via LDS: block = 4 waves = 64 f4 columns. Each chunk of 4
// c-planes is staged into LDS once (each wave global-loads ONE 1 KB plane),
// then ALL 4 waves consume the same tile, each computing a DIFFERENT
// u-quarter (14 classes, 56 acc regs/thread). x read ONCE from HBM
// (131 MB); LDS re-serves the 4x consumption (524 MB @ 69 TB/s ~ 8 us).
// fwt lives in LDS too (broadcast ds_reads, off the vmcnt queue).
// Double-buffered (8 KB), 16 barriers. Per-output-column FMA order
// (c ascending, single thread) unchanged -> bit-identical output.
// Floors: mem 240 MB @ ~6.7 TB/s = 36 us; VALU ~24 us.
// ---------------------------------------------------------------------------
__global__ __launch_bounds__(256, 4)
void seg_pred_kernel(const float* __restrict__ x,
                     const float* __restrict__ ws,
                     float* __restrict__ out)
{
    const int tid  = threadIdx.x;
    const int lane = tid & 63;
    const int wid  = tid >> 6;          // wave id 0..3
    const int u0   = wid * UQ;          // 0, 14, 28, 42
    const int j    = blockIdx.x * JT + lane;   // float4 column index

    const f4* x4   = (const f4*)x;
    f4*       out4 = (f4*)out;

    __shared__ f4    xbuf[2][4][JT];    // 2 x 4 c-planes x 64 cols = 8 KB
    __shared__ float fwts[CC * FWS];    // 64 x 56 = 14.3 KB (incl. zeroed pads)

    for (int i = tid; i < CC * FWS; i += 256)   // fwt -> LDS once
        fwts[i] = ws[WS_FWT + i];

    f4 acc[UQ];
    #pragma unroll
    for (int u = 0; u < UQ; ++u) acc[u] = (f4)0.0f;

    // prologue: stage chunk 0 (wave w loads c-plane w)
    xbuf[0][wid][lane] = x4[(size_t)wid * HW4 + j];
    __syncthreads();

    for (int t = 0; t < NCH; ++t) {
        const int buf = t & 1;
        if (t + 1 < NCH) {              // stage next chunk (issue early;
            const int c = (t + 1) * 4 + wid;    // ds_write lands pre-barrier)
            xbuf[buf ^ 1][wid][lane] = x4[(size_t)c * HW4 + j];
        }
        #pragma unroll
        for (int cc = 0; cc < 4; ++cc) {
            const int c = t * 4 + cc;
            const f4 xv = xbuf[buf][cc][lane];          // ds_read_b128
            const float* fr = &fwts[c * FWS + u0];
            #pragma unroll
            for (int u = 0; u < UQ; ++u) {
                const float w = fr[u];                  // LDS broadcast
                acc[u].x = fmaf(w, xv.x, acc[u].x);
                acc[u].y = fmaf(w, xv.y, acc[u].y);
                acc[u].z = fmaf(w, xv.z, acc[u].z);
                acc[u].w = fmaf(w, xv.w, acc[u].w);
            }
        }
        __syncthreads();                // tile consumed; next tile ready
    }

    #pragma unroll
    for (int u = 0; u < UQ; ++u)
        if (u0 + u < UU)                // wave 3 stores 11 rows
            __builtin_nontemporal_store(acc[u], &out4[(size_t)(u0 + u) * HW4 + j]);
}

extern "C" void kernel_launch(void* const* d_in, const int* in_sizes, int n_in,
                              void* d_out, int out_size, void* d_ws, size_t ws_size,
                              hipStream_t stream)
{
    const float* x          = (const float*)d_in[0];
    const float* idx_feat   = (const float*)d_in[1];
    const float* weight     = (const float*)d_in[2];
    const float* bias       = (const float*)d_in[3];
    const int*   pred_cate  = (const int*)d_in[4];
    const float* pred_score = (const float*)d_in[5];

    float* out = (float*)d_out;
    float* ws  = (float*)d_ws;

    fused12_kernel<<<UU, 256, 0, stream>>>(idx_feat, pred_cate, pred_score,
                                           weight, bias, ws, out);
    seg_pred_kernel<<<HW4 / JT, 256, 0, stream>>>(x, ws, out);  // 2048 blocks
}

// Round 9
// 316.275 us; speedup vs baseline: 1.1290x; 1.0103x over previous
//
#include <hip/hip_runtime.h>

// x        [64, 524288] f32 | idx_feat [4096,256] f32 | weight [64,256] f32
// bias     [64] f32         | pred_cate [4096] i32    | pred_score [4096] f32
// out (f32 concat): seg_pred [53*524288], unique_cate [53], fused_score [53]

#define KK   4096
#define CIN  256
#define CC   64
#define HW   524288   // 512*1024
#define HW4  (HW / 4) // float4 columns
#define UU   53
#define FWS  56       // fwt row stride (half 1 reads pad col 53: zeroed)
#define UH   27       // classes per u-half (half 0: 27, half 1: 26)
#define PD   8        // load-pipeline depth (7*216 cyc compute > 900 cyc HBM)

// ws layout (floats) — only fwt; no atomics, no memset needed
#define WS_FWT 0      // fw TRANSPOSED [64][FWS]

typedef float f4 __attribute__((ext_vector_type(4)));

// ---------------------------------------------------------------------------
// Fused stages 1+2 (UNCHANGED from round 6, incl. pad-col zeroing).
// ---------------------------------------------------------------------------
__global__ __launch_bounds__(256)
void fused12_kernel(const float* __restrict__ idx_feat,
                    const int*   __restrict__ pred_cate,
                    const float* __restrict__ pred_score,
                    const float* __restrict__ weight,
                    const float* __restrict__ bias,
                    float* __restrict__ ws,
                    float* __restrict__ out)
{
    const int u   = blockIdx.x;
    const int tid = threadIdx.x;

    __shared__ int   list[128];    // max count per class is 78 (4096 = 53*77+15)
    __shared__ int   nmatch;
    __shared__ float sumf[CIN];    // per-cin class feature sums
    __shared__ float wsum[4];      // per-wave score partials

    if (u == 0 && tid < CC) {      // zero pad cols (disjoint from all col stores)
        ws[WS_FWT + tid * FWS + 53] = 0.0f;
        ws[WS_FWT + tid * FWS + 54] = 0.0f;
        ws[WS_FWT + tid * FWS + 55] = 0.0f;
    }

    if (tid == 0) nmatch = 0;
    __syncthreads();

    // ---- Phase A: scan + compact + score ----
    float sc = 0.0f;
    #pragma unroll
    for (int k = tid; k < KK; k += 256) {       // coalesced int loads
        if (pred_cate[k] == u) {
            int pos = atomicAdd(&nmatch, 1);    // LDS atomic, ~77/block total
            list[pos] = k;
            sc += pred_score[k];
        }
    }
    // wave-reduce score (64 lanes)
    #pragma unroll
    for (int off = 32; off > 0; off >>= 1) sc += __shfl_down(sc, off);
    if ((tid & 63) == 0) wsum[tid >> 6] = sc;
    __syncthreads();                            // list + wsum complete

    // ---- Phase B: feature sums, thread owns cin = tid ----
    const int n = nmatch;                       // uniform
    float acc = 0.0f;
    #pragma unroll 4
    for (int m = 0; m < n; ++m) {
        const int k = list[m];                  // uniform LDS broadcast
        acc += idx_feat[(size_t)k * CIN + tid]; // coalesced row load
    }
    sumf[tid] = acc;
    __syncthreads();

    // ---- Phase C: fw[:,u] = (weight @ mean_u) + bias, transposed store ----
    const float inv = 1.0f / (float)n;
    const int c = tid >> 2;                     // output channel 0..63
    const int q = tid & 3;                      // quarter of the 256-dot
    float d = 0.0f;
    const int i0 = q * 64;
    #pragma unroll 8
    for (int i = 0; i < 64; ++i)
        d = fmaf(sumf[i0 + i], weight[(size_t)c * CIN + i0 + i], d);
    d += __shfl_xor(d, 1);
    d += __shfl_xor(d, 2);                      // q-group of 4 summed
    if (q == 0)
        ws[WS_FWT + c * FWS + u] = d * inv + bias[c];

    if (tid == 0) {
        out[(size_t)UU * HW + u]      = (float)u;                       // unique_cate
        out[(size_t)UU * HW + UU + u] = (wsum[0] + wsum[1] + wsum[2] + wsum[3]) * inv; // fused_score
    }
}

// ---------------------------------------------------------------------------
// Stage 3: seg_pred = fw [53,64] @ x [64, HW], 2-way u-split + EXPLICIT
// 8-deep rotating load pipeline.
// Model closure on r6 (79.7 us): VALUBusy 29% == total-FMA-cycles/device-
// cycles exactly -> per-c-iter stall ~1700 cyc (x loads NOT pipelined by
// the compiler; L3 is wiped by inter-iteration fills so x is HBM-cold).
// Fix by dataflow, not occupancy: p[8] rotating buffer, STATIC slot index
// (rule #20); slot s refilled 7 slots (~1500 compute cyc > 900 cyc HBM
// latency) before consumption -> ~zero steady-state stall even at 2
// waves/SIMD. Regs: 108 acc + 32 pipe + addr ~ 160 unified, well under the
// 256 cap of launch_bounds(256,2) -> no r4-style clamp/spill.
// Plain cached x loads (r6 proved single HBM fetch, FETCH=131 MB); nt
// stores. Per-output FMA chain (c ascending) unchanged -> bit-identical.
// Floors: mem 245 MB @ ~6.7 TB/s = 37 us; VALU 23 us.
// ---------------------------------------------------------------------------
__global__ __launch_bounds__(256, 2)
void seg_pred_kernel(const float* __restrict__ x,
                     const float* __restrict__ ws,
                     float* __restrict__ out)
{
    const int b    = blockIdx.x;
    const int half = b & 1;
    const int j    = (b >> 1) * 256 + threadIdx.x;  // float4 column index
    const int u0   = half * UH;                     // 0 or 27
    const f4* x4   = (const f4*)x;
    f4*       out4 = (f4*)out;
    const float* fwt = ws + WS_FWT + u0;

    f4 acc[UH];
    #pragma unroll
    for (int u = 0; u < UH; ++u) acc[u] = (f4)0.0f;

    // prologue: fill the 8-slot pipeline (8 loads in flight)
    f4 p[PD];
    #pragma unroll
    for (int s = 0; s < PD; ++s)
        p[s] = x4[(size_t)s * HW4 + j];

    #pragma unroll 1
    for (int t = 0; t < CC / PD; ++t) {             // 8 super-iters
        #pragma unroll
        for (int s = 0; s < PD; ++s) {              // s static -> p in regs
            const int c = t * PD + s;
            const f4 xv = p[s];                     // consume slot
            if (t < CC / PD - 1)                    // uniform branch
                p[s] = x4[(size_t)(c + PD) * HW4 + j];  // refill: used 8 slots later
            const float* fr = &fwt[c * FWS];
            #pragma unroll
            for (int u = 0; u < UH; ++u) {
                const float w = fr[u];              // uniform, consecutive (s_load)
                acc[u].x = fmaf(w, xv.x, acc[u].x); // (half 1, u=26 reads zeroed
                acc[u].y = fmaf(w, xv.y, acc[u].y); //  pad col 53, never stored)
                acc[u].z = fmaf(w, xv.z, acc[u].z);
                acc[u].w = fmaf(w, xv.w, acc[u].w);
            }
        }
    }

    #pragma unroll
    for (int u = 0; u < UH; ++u)
        if (u0 + u < UU)                            // half 1 stores 26 rows
            __builtin_nontemporal_store(acc[u], &out4[(size_t)(u0 + u) * HW4 + j]);
}

extern "C" void kernel_launch(void* const* d_in, const int* in_sizes, int n_in,
                              void* d_out, int out_size, void* d_ws, size_t ws_size,
                              hipStream_t stream)
{
    const float* x          = (const float*)d_in[0];
    const float* idx_feat   = (const float*)d_in[1];
    const float* weight     = (const float*)d_in[2];
    const float* bias       = (const float*)d_in[3];
    const int*   pred_cate  = (const int*)d_in[4];
    const float* pred_score = (const float*)d_in[5];

    float* out = (float*)d_out;
    float* ws  = (float*)d_ws;

    fused12_kernel<<<UU, 256, 0, stream>>>(idx_feat, pred_cate, pred_score,
                                           weight, bias, ws, out);
    seg_pred_kernel<<<2 * (HW4 / 256), 256, 0, stream>>>(x, ws, out);  // 1024 blocks
}

// Round 10
// 279.700 us; speedup vs baseline: 1.2766x; 1.1308x over previous
//
#include <hip/hip_runtime.h>

// x        [64, 524288] f32 | idx_feat [4096,256] f32 | weight [64,256] f32
// bias     [64] f32         | pred_cate [4096] i32    | pred_score [4096] f32
// out (f32 concat): seg_pred [53*524288], unique_cate [53], fused_score [53]

#define KK   4096
#define CIN  256
#define CC   64
#define HW   524288   // 512*1024
#define HW4  (HW / 4) // float4 columns
#define UU   53
#define FWS  56       // fwt row stride (half 1 reads pad col 53: zeroed)
#define UH   27       // classes per u-half (half 0: 27, half 1: 26)

// ws layout (floats) — only fwt; no atomics, no memset needed
#define WS_FWT 0      // fw TRANSPOSED [64][FWS]

typedef float f4 __attribute__((ext_vector_type(4)));

// ---------------------------------------------------------------------------
// Fused stages 1+2 (UNCHANGED from round 6, incl. pad-col zeroing).
// ---------------------------------------------------------------------------
__global__ __launch_bounds__(256)
void fused12_kernel(const float* __restrict__ idx_feat,
                    const int*   __restrict__ pred_cate,
                    const float* __restrict__ pred_score,
                    const float* __restrict__ weight,
                    const float* __restrict__ bias,
                    float* __restrict__ ws,
                    float* __restrict__ out)
{
    const int u   = blockIdx.x;
    const int tid = threadIdx.x;

    __shared__ int   list[128];    // max count per class is 78 (4096 = 53*77+15)
    __shared__ int   nmatch;
    __shared__ float sumf[CIN];    // per-cin class feature sums
    __shared__ float wsum[4];      // per-wave score partials

    if (u == 0 && tid < CC) {      // zero pad cols (disjoint from all col stores)
        ws[WS_FWT + tid * FWS + 53] = 0.0f;
        ws[WS_FWT + tid * FWS + 54] = 0.0f;
        ws[WS_FWT + tid * FWS + 55] = 0.0f;
    }

    if (tid == 0) nmatch = 0;
    __syncthreads();

    // ---- Phase A: scan + compact + score ----
    float sc = 0.0f;
    #pragma unroll
    for (int k = tid; k < KK; k += 256) {       // coalesced int loads
        if (pred_cate[k] == u) {
            int pos = atomicAdd(&nmatch, 1);    // LDS atomic, ~77/block total
            list[pos] = k;
            sc += pred_score[k];
        }
    }
    // wave-reduce score (64 lanes)
    #pragma unroll
    for (int off = 32; off > 0; off >>= 1) sc += __shfl_down(sc, off);
    if ((tid & 63) == 0) wsum[tid >> 6] = sc;
    __syncthreads();                            // list + wsum complete

    // ---- Phase B: feature sums, thread owns cin = tid ----
    const int n = nmatch;                       // uniform
    float acc = 0.0f;
    #pragma unroll 4
    for (int m = 0; m < n; ++m) {
        const int k = list[m];                  // uniform LDS broadcast
        acc += idx_feat[(size_t)k * CIN + tid]; // coalesced row load
    }
    sumf[tid] = acc;
    __syncthreads();

    // ---- Phase C: fw[:,u] = (weight @ mean_u) + bias, transposed store ----
    const float inv = 1.0f / (float)n;
    const int c = tid >> 2;                     // output channel 0..63
    const int q = tid & 3;                      // quarter of the 256-dot
    float d = 0.0f;
    const int i0 = q * 64;
    #pragma unroll 8
    for (int i = 0; i < 64; ++i)
        d = fmaf(sumf[i0 + i], weight[(size_t)c * CIN + i0 + i], d);
    d += __shfl_xor(d, 1);
    d += __shfl_xor(d, 2);                      // q-group of 4 summed
    if (q == 0)
        ws[WS_FWT + c * FWS + u] = d * inv + bias[c];

    if (tid == 0) {
        out[(size_t)UU * HW + u]      = (float)u;                       // unique_cate
        out[(size_t)UU * HW + UU + u] = (wsum[0] + wsum[1] + wsum[2] + wsum[3]) * inv; // fused_score
    }
}

// ---------------------------------------------------------------------------
// Stage 3: seg_pred = fw [53,64] @ x [64, HW], u-SPLIT 2-way — EXACT round-6
// structure (best measured: 79.7 us, FETCH 131 MB single HBM pass, WRITE
// 108.5 MB clean) with ONE change: c-loop unroll 2 -> 4, lb (256,4)->(256,3).
// Stall model (r6 closure): VALUBusy 31% == pure-FMA share exactly; unroll-2
// load->consume window = 216 cyc x 2 x 2.64 waves/SIMD ~ 570 cyc < ~900 cyc
// cold-HBM latency -> stall every pair. Unroll 4 doubles the window to
// ~1140 cyc > latency; regs 168 -> ~150-170 keeps the SAME 3 waves/SIMD
// (512-reg pool), so ILP doubles at no occupancy cost. lb(256,3) is the
// honest target (r6's (256,4) was silently violated at 168 regs; r4 showed
// a forced clamp can spill). Plain cached x loads; nt stores.
// Per-output FMA chain (c ascending) unchanged -> bit-identical.
// Floors: mem 245 MB @ ~6.7 TB/s = 37 us; VALU 23 us.
// ---------------------------------------------------------------------------
__global__ __launch_bounds__(256, 3)
void seg_pred_kernel(const float* __restrict__ x,
                     const float* __restrict__ ws,
                     float* __restrict__ out)
{
    const int b    = blockIdx.x;
    const int half = b & 1;
    const int j    = (b >> 1) * 256 + threadIdx.x;  // float4 column index
    const int u0   = half * UH;                     // 0 or 27
    const f4* x4   = (const f4*)x;
    f4*       out4 = (f4*)out;
    const float* fwt = ws + WS_FWT + u0;

    f4 acc[UH];
    #pragma unroll
    for (int u = 0; u < UH; ++u) acc[u] = (f4)0.0f;

    #pragma unroll 4
    for (int c = 0; c < CC; ++c) {
        const f4 xv = x4[(size_t)c * HW4 + j];       // plain load: L2/L3 allocate
        #pragma unroll
        for (int u = 0; u < UH; ++u) {
            const float w = fwt[c * FWS + u];        // uniform, consecutive
            acc[u].x = fmaf(w, xv.x, acc[u].x);      // (half 1, u=26 reads zeroed
            acc[u].y = fmaf(w, xv.y, acc[u].y);      //  pad col 53, never stored)
            acc[u].z = fmaf(w, xv.z, acc[u].z);
            acc[u].w = fmaf(w, xv.w, acc[u].w);
        }
    }

    #pragma unroll
    for (int u = 0; u < UH; ++u)
        if (u0 + u < UU)                             // half 1 stores 26 rows
            __builtin_nontemporal_store(acc[u], &out4[(size_t)(u0 + u) * HW4 + j]);
}

extern "C" void kernel_launch(void* const* d_in, const int* in_sizes, int n_in,
                              void* d_out, int out_size, void* d_ws, size_t ws_size,
                              hipStream_t stream)
{
    const float* x          = (const float*)d_in[0];
    const float* idx_feat   = (const float*)d_in[1];
    const float* weight     = (const float*)d_in[2];
    const float* bias       = (const float*)d_in[3];
    const int*   pred_cate  = (const int*)d_in[4];
    const float* pred_score = (const float*)d_in[5];

    float* out = (float*)d_out;
    float* ws  = (float*)d_ws;

    fused12_kernel<<<UU, 256, 0, stream>>>(idx_feat, pred_cate, pred_score,
                                           weight, bias, ws, out);
    seg_pred_kernel<<<2 * (HW4 / 256), 256, 0, stream>>>(x, ws, out);  // 1024 blocks
}